// Round 4
// baseline (188.699 us; speedup 1.0000x reference)
//
#include <hip/hip_runtime.h>
#include <stdint.h>

// Workspace byte offsets
#define OFF_W1  0        // 1024*32 u32 packed sign bits (784 bits + zero pad)
#define OFF_W2  131072
#define OFF_W3  262144
#define OFF_WFC 393216   // 10*32 u32
#define OFF_T1  395264   // 1024 int32 popcount thresholds
#define OFF_T2  399360
#define OFF_T3  403456
#define OFF_SFC 407552   // double: mean|wfc|
// v4: four 1 MB activation stages (8192 rows x 128 B), DISTINCT buffers so no
// address is ever s_loaded before being vector-written (K$ stale-free).
#define OFF_S0  409600   // packed x
#define OFF_S1  1458176  // act1
#define OFF_S2  2506752  // act2
#define OFF_S3  3555328  // act3
#define WS_NEED_V4 4603904u
#define RWS 16           // rows per block in fused kernel

typedef uint32_t u32x16 __attribute__((ext_vector_type(16)));

// ---------------------------------------------------------------------------
// Prep — one dispatch does W-pack + thresholds + wfc. 385 blocks. (unchanged)
// ---------------------------------------------------------------------------
__global__ __launch_bounds__(256) void bnn_prep(
    const float* __restrict__ w1, const float* __restrict__ b1, const float* __restrict__ g1,
    const float* __restrict__ be1, const float* __restrict__ m1, const float* __restrict__ v1,
    const float* __restrict__ w2, const float* __restrict__ b2, const float* __restrict__ g2,
    const float* __restrict__ be2, const float* __restrict__ m2, const float* __restrict__ v2,
    const float* __restrict__ w3, const float* __restrict__ b3, const float* __restrict__ g3,
    const float* __restrict__ be3, const float* __restrict__ m3, const float* __restrict__ v3,
    const float* __restrict__ wfc,
    uint32_t* __restrict__ ws)
{
    const int blk  = blockIdx.x;
    const int t    = threadIdx.x;
    const int lane = t & 63;
    const int wv   = t >> 6;

    if (blk < 384) {
        const int gid = blk * 256 + t;      // 0..98303
        const int l   = gid >> 15;          // layer 0..2 (32768 words each)
        const int rem = gid & 32767;
        const int o   = rem >> 5;           // channel
        const int k   = rem & 31;           // word within channel
        const float *w, *bb, *g, *be, *m, *v;
        int K; uint32_t* Wp; int* T;
        if (l == 0)      { w=w1; bb=b1; g=g1; be=be1; m=m1; v=v1; K=784;  Wp = ws + OFF_W1/4; T = (int*)(ws + OFF_T1/4); }
        else if (l == 1) { w=w2; bb=b2; g=g2; be=be2; m=m2; v=v2; K=1024; Wp = ws + OFF_W2/4; T = (int*)(ws + OFF_T2/4); }
        else             { w=w3; bb=b3; g=g3; be=be3; m=m3; v=v3; K=1024; Wp = ws + OFF_W3/4; T = (int*)(ws + OFF_T3/4); }

        const int base = 32 * k;
        uint32_t bits = 0;
        double s = 0.0;
        if (base < K) {
            const float4* p = (const float4*)(w + (size_t)o * K + base);
            const int n4 = (K - base >= 32) ? 8 : 4;   // K=784, k=24 -> 16 elems
            for (int i = 0; i < n4; ++i) {
                float4 q = p[i];
                bits |= (q.x >= 0.0f) ? (1u << (4*i + 0)) : 0u;
                bits |= (q.y >= 0.0f) ? (1u << (4*i + 1)) : 0u;
                bits |= (q.z >= 0.0f) ? (1u << (4*i + 2)) : 0u;
                bits |= (q.w >= 0.0f) ? (1u << (4*i + 3)) : 0u;
                s += fabs((double)q.x) + fabs((double)q.y)
                   + fabs((double)q.z) + fabs((double)q.w);
            }
        }
        // half-wave (32-lane) xor tree: all lanes of the half get channel sum
        #pragma unroll
        for (int mask = 1; mask <= 16; mask <<= 1)
            s += __shfl_xor(s, mask, 64);
        if (k == 0) {
            double scale = s / (double)K;                        // mean|w| > 0
            double r = (double)g[o] / sqrt((double)v[o] + 1e-5); // > 0
            double tt = (((double)m[o] - (double)bb[o]) * r - (double)be[o]) / (scale * r);
            double C  = ceil(tt);                                // dot >= C
            double Td = floor(((double)K - C) * 0.5);            // p <= Td
            Td = fmax(fmin(Td, 100000.0), -1.0);
            T[o] = (int)Td;
        }
        Wp[(size_t)o * 32 + k] = bits;
    } else {
        // wfc: 320 words (10 ch x 32); thread t does word t and (t<64) t+256
        uint32_t* Wp = ws + OFF_WFC/4;
        double s = 0.0;
        {
            const int o = t >> 5, k = t & 31;
            const float4* p = (const float4*)(wfc + o * 1024 + 32 * k);
            uint32_t bits = 0;
            #pragma unroll
            for (int i = 0; i < 8; ++i) {
                float4 q = p[i];
                bits |= (q.x >= 0.0f) ? (1u << (4*i + 0)) : 0u;
                bits |= (q.y >= 0.0f) ? (1u << (4*i + 1)) : 0u;
                bits |= (q.z >= 0.0f) ? (1u << (4*i + 2)) : 0u;
                bits |= (q.w >= 0.0f) ? (1u << (4*i + 3)) : 0u;
                s += fabs((double)q.x) + fabs((double)q.y)
                   + fabs((double)q.z) + fabs((double)q.w);
            }
            Wp[t] = bits;
        }
        if (t < 64) {
            const int t2 = t + 256;
            const int o = t2 >> 5, k = t2 & 31;
            const float4* p = (const float4*)(wfc + o * 1024 + 32 * k);
            uint32_t bits = 0;
            #pragma unroll
            for (int i = 0; i < 8; ++i) {
                float4 q = p[i];
                bits |= (q.x >= 0.0f) ? (1u << (4*i + 0)) : 0u;
                bits |= (q.y >= 0.0f) ? (1u << (4*i + 1)) : 0u;
                bits |= (q.z >= 0.0f) ? (1u << (4*i + 2)) : 0u;
                bits |= (q.w >= 0.0f) ? (1u << (4*i + 3)) : 0u;
                s += fabs((double)q.x) + fabs((double)q.y)
                   + fabs((double)q.z) + fabs((double)q.w);
            }
            Wp[t2] = bits;
        }
        __shared__ double red[4];
        #pragma unroll
        for (int off = 32; off > 0; off >>= 1) s += __shfl_down(s, off, 64);
        if (lane == 0) red[wv] = s;
        __syncthreads();
        if (t == 0)
            *(double*)(ws + OFF_SFC/4) = (red[0] + red[1] + red[2] + red[3]) / 10240.0;
    }
}

// ---------------------------------------------------------------------------
// Fused network kernel v4 (R13): A in SGPRs via forced s_load; acts ping-pong
// through 4 distinct global stage buffers (per-block 2 KB, K$/L2-resident).
// R3 evidence: VGPR_Count=56 despite a 128-reg budget -> compiler AGPR-offloads
// the W arrays and pays v_accvgpr_read per use (+64 VALU/row), matching the
// measured 44us VALU busy vs the 20.5us floor; LDS broadcast of A added ~31us
// of LDS-pipe busy. Moving A to SGPRs (v_xor v,s,v) empties the LDS pipe AND
// drops VGPR pressure so W stays in arch VGPRs.
// K$ correctness: each stage buffer is written (vector, write-through to L2),
// then __syncthreads() (drains vmcnt), then s_loaded for the FIRST time in the
// kernel -> K$ miss -> fresh from L2. AQL dispatch acquire invalidates K$
// across bench iterations.
// ---------------------------------------------------------------------------
__global__
__attribute__((amdgpu_flat_work_group_size(512, 512), amdgpu_waves_per_eu(4, 4)))
void bnn_fused(
    const float* __restrict__ x,
    uint32_t* __restrict__ ws,
    const float* __restrict__ bfc,
    float* __restrict__ out)
{
    const int t    = threadIdx.x;
    const int lane = t & 63;
    const int wv   = t >> 6;            // 0..7
    const int row0 = blockIdx.x * RWS;

    uint32_t* S0 = ws + OFF_S0/4;
    uint32_t* S1 = ws + OFF_S1/4;
    uint32_t* S2 = ws + OFF_S2/4;
    uint32_t* S3 = ws + OFF_S3/4;

    // ---- input pack: wave wv ballots rows wv and wv+8 straight to S0 ----
    #pragma unroll
    for (int rr = 0; rr < 2; ++rr) {
        const int r = wv + 8 * rr;
        const float* xr = x + (size_t)(row0 + r) * 784;
        uint32_t* dst = S0 + (size_t)(row0 + r) * 32;
        #pragma unroll
        for (int k = 0; k < 13; ++k) {
            const int idx = k * 64 + lane;
            const bool bit = (idx < 784) && (xr[idx] >= 0.5f);
            unsigned long long m = __ballot(bit);
            if (lane == 0) *(uint64_t*)(dst + 2 * k) = m;
        }
        if (lane == 0) {
            *(uint64_t*)(dst + 26) = 0ull;
            *(uint64_t*)(dst + 28) = 0ull;
            *(uint64_t*)(dst + 30) = 0ull;
        }
    }
    __syncthreads();   // drains vmcnt -> S0 visible in L2 before s_loads

    const uint32_t* Wbase[3] = { ws + OFF_W1/4, ws + OFF_W2/4, ws + OFF_W3/4 };
    const int*      Tbase[3] = { (const int*)(ws + OFF_T1/4), (const int*)(ws + OFF_T2/4), (const int*)(ws + OFF_T3/4) };
    const uint32_t* Sin [3]  = { S0, S1, S2 };
    uint32_t*       Sout[3]  = { S1, S2, S3 };

    const int c0 = t, c1 = t + 512;

    #pragma unroll
    for (int l = 0; l < 3; ++l) {
        uint32_t W0[32], W1[32];
        {
            const uint4* p0 = (const uint4*)(Wbase[l] + (size_t)c0 * 32);
            const uint4* p1 = (const uint4*)(Wbase[l] + (size_t)c1 * 32);
            #pragma unroll
            for (int i = 0; i < 8; ++i) { ((uint4*)W0)[i] = p0[i]; ((uint4*)W1)[i] = p1[i]; }
        }
        const int T0 = Tbase[l][c0];
        const int T1 = Tbase[l][c1];
        const uint32_t* abase = Sin[l] + (size_t)row0 * 32;   // block-uniform
        uint32_t*       obase = Sout[l] + (size_t)row0 * 32;

        #pragma unroll
        for (int r = 0; r < RWS; ++r) {
            const uint32_t* ar = abase + r * 32;
            u32x16 alo, ahi;                       // A row in 32 SGPRs
            asm volatile("s_load_dwordx16 %0, %2, 0x0\n\t"
                         "s_load_dwordx16 %1, %2, 0x40\n\t"
                         "s_waitcnt lgkmcnt(0)"
                         : "=s"(alo), "=s"(ahi) : "s"(ar) : "memory");
            int pa = 0, pb = 0, pc = 0, pd = 0;
            #pragma unroll
            for (int i = 0; i < 16; ++i) {
                pa += __popc(alo[i] ^ W0[i]);
                pb += __popc(ahi[i] ^ W0[i + 16]);
                pc += __popc(alo[i] ^ W1[i]);
                pd += __popc(ahi[i] ^ W1[i + 16]);
            }
            unsigned long long m0 = __ballot((pa + pb) <= T0);
            unsigned long long m1 = __ballot((pc + pd) <= T1);
            if (lane == 0) {
                *(uint64_t*)(obase + r * 32 + 2 * wv)      = m0;
                *(uint64_t*)(obase + r * 32 + 16 + 2 * wv) = m1;
            }
        }
        __syncthreads();   // drain stores of stage l+1 before its s_loads
    }

    // ---- FC tail: one (row, channel) per thread; act3 via vector loads ----
    if (t < RWS * 10) {
        const float sfc = (float)(*(const double*)(ws + OFF_SFC/4));
        const uint32_t* Wfc = ws + OFF_WFC/4;
        const int r = t / 10, ch = t % 10;
        uint32_t A[32];
        const uint4* ap = (const uint4*)(S3 + (size_t)(row0 + r) * 32);
        #pragma unroll
        for (int i = 0; i < 8; ++i) ((uint4*)A)[i] = ap[i];
        const uint32_t* wrow = Wfc + ch * 32;
        int p = 0;
        #pragma unroll
        for (int i = 0; i < 32; ++i) p += __popc(A[i] ^ wrow[i]);
        out[(size_t)(row0 + r) * 10 + ch] = (float)(1024 - 2 * p) * sfc + bfc[ch];
    }
}

// ---------------------------------------------------------------------------
// FALLBACK fused (R2 LDS version) — used only if ws too small for v4 stages.
// ---------------------------------------------------------------------------
__global__ __launch_bounds__(512) void bnn_fused_lds(
    const float* __restrict__ x,
    const uint32_t* __restrict__ ws,
    const float* __restrict__ bfc,
    float* __restrict__ out)
{
    __shared__ alignas(16) uint32_t bufA[RWS][32];
    __shared__ alignas(16) uint32_t bufB[RWS][32];
    const int t    = threadIdx.x;
    const int lane = t & 63;
    const int wv   = t >> 6;
    const int row0 = blockIdx.x * RWS;

    #pragma unroll
    for (int rr = 0; rr < 2; ++rr) {
        const int r = wv + 8 * rr;
        const float* xr = x + (size_t)(row0 + r) * 784;
        #pragma unroll
        for (int k = 0; k < 13; ++k) {
            const int idx = k * 64 + lane;
            const bool bit = (idx < 784) && (xr[idx] >= 0.5f);
            unsigned long long m = __ballot(bit);
            if (lane == 0) *(uint64_t*)(&bufA[r][2 * k]) = m;
        }
        if (lane == 0) {
            *(uint64_t*)(&bufA[r][26]) = 0ull;
            *(uint64_t*)(&bufA[r][28]) = 0ull;
            *(uint64_t*)(&bufA[r][30]) = 0ull;
        }
    }
    __syncthreads();

    const uint32_t* Wbase[3] = { ws + OFF_W1/4, ws + OFF_W2/4, ws + OFF_W3/4 };
    const int*      Tbase[3] = { (const int*)(ws + OFF_T1/4), (const int*)(ws + OFF_T2/4), (const int*)(ws + OFF_T3/4) };

    uint32_t (*cur)[32] = bufA;
    uint32_t (*nxt)[32] = bufB;
    const int c0 = t, c1 = t + 512;

    for (int l = 0; l < 3; ++l) {
        uint32_t W0[32], W1[32];
        {
            const uint4* p0 = (const uint4*)(Wbase[l] + (size_t)c0 * 32);
            const uint4* p1 = (const uint4*)(Wbase[l] + (size_t)c1 * 32);
            #pragma unroll
            for (int i = 0; i < 8; ++i) { ((uint4*)W0)[i] = p0[i]; ((uint4*)W1)[i] = p1[i]; }
        }
        const int T0 = Tbase[l][c0];
        const int T1 = Tbase[l][c1];

        for (int r = 0; r < RWS; ++r) {
            uint32_t A[32];
            #pragma unroll
            for (int i = 0; i < 8; ++i) ((uint4*)A)[i] = ((const uint4*)cur[r])[i];
            int pa = 0, pb = 0, pc = 0, pd = 0;
            #pragma unroll
            for (int i = 0; i < 16; ++i) {
                pa += __popc(A[i]      ^ W0[i]);
                pb += __popc(A[i + 16] ^ W0[i + 16]);
                pc += __popc(A[i]      ^ W1[i]);
                pd += __popc(A[i + 16] ^ W1[i + 16]);
            }
            unsigned long long m0 = __ballot((pa + pb) <= T0);
            unsigned long long m1 = __ballot((pc + pd) <= T1);
            if (lane == 0) {
                *(uint64_t*)(&nxt[r][2 * wv])      = m0;
                *(uint64_t*)(&nxt[r][16 + 2 * wv]) = m1;
            }
        }
        __syncthreads();
        uint32_t (*tmp)[32] = cur; cur = nxt; nxt = tmp;
    }

    if (t < RWS * 10) {
        const float sfc = (float)(*(const double*)(ws + OFF_SFC/4));
        const uint32_t* Wfc = ws + OFF_WFC/4;
        const int r = t / 10, ch = t % 10;
        const uint32_t* wrow = Wfc + ch * 32;
        int p = 0;
        #pragma unroll
        for (int i = 0; i < 32; ++i) p += __popc(cur[r][i] ^ wrow[i]);
        out[(size_t)(row0 + r) * 10 + ch] = (float)(1024 - 2 * p) * sfc + bfc[ch];
    }
}

extern "C" void kernel_launch(void* const* d_in, const int* in_sizes, int n_in,
                              void* d_out, int out_size, void* d_ws, size_t ws_size,
                              hipStream_t stream) {
    const float* x   = (const float*)d_in[0];
    const float* w1  = (const float*)d_in[1];
    const float* b1  = (const float*)d_in[2];
    const float* g1  = (const float*)d_in[3];
    const float* be1 = (const float*)d_in[4];
    const float* m1  = (const float*)d_in[5];
    const float* v1  = (const float*)d_in[6];
    const float* w2  = (const float*)d_in[7];
    const float* b2  = (const float*)d_in[8];
    const float* g2  = (const float*)d_in[9];
    const float* be2 = (const float*)d_in[10];
    const float* m2  = (const float*)d_in[11];
    const float* v2  = (const float*)d_in[12];
    const float* w3  = (const float*)d_in[13];
    const float* b3  = (const float*)d_in[14];
    const float* g3  = (const float*)d_in[15];
    const float* be3 = (const float*)d_in[16];
    const float* m3  = (const float*)d_in[17];
    const float* v3  = (const float*)d_in[18];
    const float* wfc = (const float*)d_in[19];
    const float* bfc = (const float*)d_in[20];
    uint32_t* ws = (uint32_t*)d_ws;
    float* out = (float*)d_out;

    // 2 dispatches total: weight prep, then the whole net fused.
    bnn_prep<<<385, 256, 0, stream>>>(
        w1, b1, g1, be1, m1, v1,
        w2, b2, g2, be2, m2, v2,
        w3, b3, g3, be3, m3, v3,
        wfc, ws);

    if (ws_size >= (size_t)WS_NEED_V4) {
        bnn_fused<<<8192 / RWS, 512, 0, stream>>>(x, ws, bfc, out);
    } else {
        bnn_fused_lds<<<8192 / RWS, 512, 0, stream>>>(x, ws, bfc, out);
    }
}

// Round 5
// 176.825 us; speedup vs baseline: 1.0672x; 1.0672x over previous
//
#include <hip/hip_runtime.h>
#include <stdint.h>

// Workspace byte offsets
#define OFF_W1  0        // 1024*32 u32 packed sign bits (784 bits + zero pad)
#define OFF_W2  131072
#define OFF_W3  262144
#define OFF_WFC 393216   // 10*32 u32
#define OFF_T1  395264   // 1024 int32 popcount thresholds
#define OFF_T2  399360
#define OFF_T3  403456
#define OFF_SFC 407552   // double: mean|wfc|
// Four 1 MB activation stages (8192 rows x 128 B), DISTINCT buffers so no
// address is ever s_loaded before being vector-written (K$ stale-free).
#define OFF_S0  409600   // packed x
#define OFF_S1  1458176  // act1
#define OFF_S2  2506752  // act2
#define OFF_S3  3555328  // act3
#define WS_NEED_V4 4603904u
#define RWS 16           // rows per block in fused kernel

typedef uint32_t u32x16 __attribute__((ext_vector_type(16)));

// ---------------------------------------------------------------------------
// Prep — one dispatch does W-pack + thresholds + wfc. 385 blocks. (unchanged)
// ---------------------------------------------------------------------------
__global__ __launch_bounds__(256) void bnn_prep(
    const float* __restrict__ w1, const float* __restrict__ b1, const float* __restrict__ g1,
    const float* __restrict__ be1, const float* __restrict__ m1, const float* __restrict__ v1,
    const float* __restrict__ w2, const float* __restrict__ b2, const float* __restrict__ g2,
    const float* __restrict__ be2, const float* __restrict__ m2, const float* __restrict__ v2,
    const float* __restrict__ w3, const float* __restrict__ b3, const float* __restrict__ g3,
    const float* __restrict__ be3, const float* __restrict__ m3, const float* __restrict__ v3,
    const float* __restrict__ wfc,
    uint32_t* __restrict__ ws)
{
    const int blk  = blockIdx.x;
    const int t    = threadIdx.x;
    const int lane = t & 63;
    const int wv   = t >> 6;

    if (blk < 384) {
        const int gid = blk * 256 + t;      // 0..98303
        const int l   = gid >> 15;          // layer 0..2 (32768 words each)
        const int rem = gid & 32767;
        const int o   = rem >> 5;           // channel
        const int k   = rem & 31;           // word within channel
        const float *w, *bb, *g, *be, *m, *v;
        int K; uint32_t* Wp; int* T;
        if (l == 0)      { w=w1; bb=b1; g=g1; be=be1; m=m1; v=v1; K=784;  Wp = ws + OFF_W1/4; T = (int*)(ws + OFF_T1/4); }
        else if (l == 1) { w=w2; bb=b2; g=g2; be=be2; m=m2; v=v2; K=1024; Wp = ws + OFF_W2/4; T = (int*)(ws + OFF_T2/4); }
        else             { w=w3; bb=b3; g=g3; be=be3; m=m3; v=v3; K=1024; Wp = ws + OFF_W3/4; T = (int*)(ws + OFF_T3/4); }

        const int base = 32 * k;
        uint32_t bits = 0;
        double s = 0.0;
        if (base < K) {
            const float4* p = (const float4*)(w + (size_t)o * K + base);
            const int n4 = (K - base >= 32) ? 8 : 4;   // K=784, k=24 -> 16 elems
            for (int i = 0; i < n4; ++i) {
                float4 q = p[i];
                bits |= (q.x >= 0.0f) ? (1u << (4*i + 0)) : 0u;
                bits |= (q.y >= 0.0f) ? (1u << (4*i + 1)) : 0u;
                bits |= (q.z >= 0.0f) ? (1u << (4*i + 2)) : 0u;
                bits |= (q.w >= 0.0f) ? (1u << (4*i + 3)) : 0u;
                s += fabs((double)q.x) + fabs((double)q.y)
                   + fabs((double)q.z) + fabs((double)q.w);
            }
        }
        // half-wave (32-lane) xor tree: all lanes of the half get channel sum
        #pragma unroll
        for (int mask = 1; mask <= 16; mask <<= 1)
            s += __shfl_xor(s, mask, 64);
        if (k == 0) {
            double scale = s / (double)K;                        // mean|w| > 0
            double r = (double)g[o] / sqrt((double)v[o] + 1e-5); // > 0
            double tt = (((double)m[o] - (double)bb[o]) * r - (double)be[o]) / (scale * r);
            double C  = ceil(tt);                                // dot >= C
            double Td = floor(((double)K - C) * 0.5);            // p <= Td
            Td = fmax(fmin(Td, 100000.0), -1.0);
            T[o] = (int)Td;
        }
        Wp[(size_t)o * 32 + k] = bits;
    } else {
        // wfc: 320 words (10 ch x 32); thread t does word t and (t<64) t+256
        uint32_t* Wp = ws + OFF_WFC/4;
        double s = 0.0;
        {
            const int o = t >> 5, k = t & 31;
            const float4* p = (const float4*)(wfc + o * 1024 + 32 * k);
            uint32_t bits = 0;
            #pragma unroll
            for (int i = 0; i < 8; ++i) {
                float4 q = p[i];
                bits |= (q.x >= 0.0f) ? (1u << (4*i + 0)) : 0u;
                bits |= (q.y >= 0.0f) ? (1u << (4*i + 1)) : 0u;
                bits |= (q.z >= 0.0f) ? (1u << (4*i + 2)) : 0u;
                bits |= (q.w >= 0.0f) ? (1u << (4*i + 3)) : 0u;
                s += fabs((double)q.x) + fabs((double)q.y)
                   + fabs((double)q.z) + fabs((double)q.w);
            }
            Wp[t] = bits;
        }
        if (t < 64) {
            const int t2 = t + 256;
            const int o = t2 >> 5, k = t2 & 31;
            const float4* p = (const float4*)(wfc + o * 1024 + 32 * k);
            uint32_t bits = 0;
            #pragma unroll
            for (int i = 0; i < 8; ++i) {
                float4 q = p[i];
                bits |= (q.x >= 0.0f) ? (1u << (4*i + 0)) : 0u;
                bits |= (q.y >= 0.0f) ? (1u << (4*i + 1)) : 0u;
                bits |= (q.z >= 0.0f) ? (1u << (4*i + 2)) : 0u;
                bits |= (q.w >= 0.0f) ? (1u << (4*i + 3)) : 0u;
                s += fabs((double)q.x) + fabs((double)q.y)
                   + fabs((double)q.z) + fabs((double)q.w);
            }
            Wp[t2] = bits;
        }
        __shared__ double red[4];
        #pragma unroll
        for (int off = 32; off > 0; off >>= 1) s += __shfl_down(s, off, 64);
        if (lane == 0) red[wv] = s;
        __syncthreads();
        if (t == 0)
            *(double*)(ws + OFF_SFC/4) = (red[0] + red[1] + red[2] + red[3]) / 10240.0;
    }
}

// ---------------------------------------------------------------------------
// Fused network kernel v5 (R14): ONE channel per thread, 1024-thread blocks.
// R2-R4 evidence: with 2 ch/thread (W demand 64 words + A) the allocator
// always AGPR-offloads W (VGPR_Count 48-56 across three coaxing attempts) and
// pays v_accvgpr_read per use -> VALU busy 42us vs 20.5us floor. Fix by
// construction: per-thread working set = W[32] + ~20 misc < 64 VGPRs, so the
// compiler's preferred 64-reg/8-wave tier holds W arch-resident with zero
// offload. Grid 512 x 1024 thr = 32 waves/CU (8/SIMD, was 4) -> double the
// latency hiding for the per-row blocking s_load of A.
//   - A in SGPRs via forced s_load_dwordx16 pairs (2 KB/block slice, K$-res).
//   - acts ping-pong through 4 distinct global stage buffers (no LDS at all).
//   - wave = 64 consecutive channels => __ballot IS the output word pair.
// K$ correctness: each stage buffer is vector-written, __syncthreads (drains
// vmcnt), then s_loaded for the FIRST time in-kernel -> K$ miss -> fresh from
// L2. AQL dispatch acquire invalidates K$ across bench iterations.
// ---------------------------------------------------------------------------
__global__ __launch_bounds__(1024) void bnn_fused(
    const float* __restrict__ x,
    uint32_t* __restrict__ ws,
    const float* __restrict__ bfc,
    float* __restrict__ out)
{
    const int t    = threadIdx.x;
    const int lane = t & 63;
    const int wv   = t >> 6;            // 0..15
    const int row0 = blockIdx.x * RWS;

    uint32_t* S0 = ws + OFF_S0/4;
    uint32_t* S1 = ws + OFF_S1/4;
    uint32_t* S2 = ws + OFF_S2/4;
    uint32_t* S3 = ws + OFF_S3/4;

    // ---- input pack: wave wv ballots row row0+wv straight to S0 ----
    {
        const float* xr = x + (size_t)(row0 + wv) * 784;
        uint32_t* dst = S0 + (size_t)(row0 + wv) * 32;
        #pragma unroll
        for (int k = 0; k < 13; ++k) {
            const int idx = k * 64 + lane;
            const bool bit = (idx < 784) && (xr[idx] >= 0.5f);
            unsigned long long m = __ballot(bit);
            if (lane == 0) *(uint64_t*)(dst + 2 * k) = m;
        }
        if (lane == 0) {
            *(uint64_t*)(dst + 26) = 0ull;
            *(uint64_t*)(dst + 28) = 0ull;
            *(uint64_t*)(dst + 30) = 0ull;
        }
    }
    __syncthreads();   // drains vmcnt -> S0 visible in L2 before s_loads

    const uint32_t* Wbase[3] = { ws + OFF_W1/4, ws + OFF_W2/4, ws + OFF_W3/4 };
    const int*      Tbase[3] = { (const int*)(ws + OFF_T1/4), (const int*)(ws + OFF_T2/4), (const int*)(ws + OFF_T3/4) };
    const uint32_t* Sin [3]  = { S0, S1, S2 };
    uint32_t*       Sout[3]  = { S1, S2, S3 };

    const int c = t;   // this thread's channel, 0..1023

    #pragma unroll
    for (int l = 0; l < 3; ++l) {
        uint32_t W[32];
        {
            const uint4* p = (const uint4*)(Wbase[l] + (size_t)c * 32);
            #pragma unroll
            for (int i = 0; i < 8; ++i) ((uint4*)W)[i] = p[i];
        }
        const int Tc = Tbase[l][c];
        const uint32_t* abase = Sin[l] + (size_t)row0 * 32;   // block-uniform
        uint32_t*       obase = Sout[l] + (size_t)row0 * 32;

        #pragma unroll
        for (int r = 0; r < RWS; ++r) {
            const uint32_t* ar = abase + r * 32;
            u32x16 alo, ahi;                       // A row in 32 SGPRs
            asm volatile("s_load_dwordx16 %0, %2, 0x0\n\t"
                         "s_load_dwordx16 %1, %2, 0x40\n\t"
                         "s_waitcnt lgkmcnt(0)"
                         : "=s"(alo), "=s"(ahi) : "s"(ar) : "memory");
            int p = 0;
            #pragma unroll
            for (int i = 0; i < 16; ++i) p += __popc(alo[i] ^ W[i]);
            #pragma unroll
            for (int i = 0; i < 16; ++i) p += __popc(ahi[i] ^ W[i + 16]);
            unsigned long long m = __ballot(p <= Tc);
            if (lane == 0)
                *(uint64_t*)(obase + r * 32 + 2 * wv) = m;
        }
        __syncthreads();   // drain stores of stage l+1 before its s_loads
    }

    // ---- FC tail: one (row, channel) per thread; act3 via vector loads ----
    if (t < RWS * 10) {
        const float sfc = (float)(*(const double*)(ws + OFF_SFC/4));
        const uint32_t* Wfc = ws + OFF_WFC/4;
        const int r = t / 10, ch = t % 10;
        uint32_t A[32];
        const uint4* ap = (const uint4*)(S3 + (size_t)(row0 + r) * 32);
        #pragma unroll
        for (int i = 0; i < 8; ++i) ((uint4*)A)[i] = ap[i];
        const uint32_t* wrow = Wfc + ch * 32;
        int p = 0;
        #pragma unroll
        for (int i = 0; i < 32; ++i) p += __popc(A[i] ^ wrow[i]);
        out[(size_t)(row0 + r) * 10 + ch] = (float)(1024 - 2 * p) * sfc + bfc[ch];
    }
}

// ---------------------------------------------------------------------------
// FALLBACK fused (R2 LDS version) — used only if ws too small for v4 stages.
// ---------------------------------------------------------------------------
__global__ __launch_bounds__(512) void bnn_fused_lds(
    const float* __restrict__ x,
    const uint32_t* __restrict__ ws,
    const float* __restrict__ bfc,
    float* __restrict__ out)
{
    __shared__ alignas(16) uint32_t bufA[RWS][32];
    __shared__ alignas(16) uint32_t bufB[RWS][32];
    const int t    = threadIdx.x;
    const int lane = t & 63;
    const int wv   = t >> 6;
    const int row0 = blockIdx.x * RWS;

    #pragma unroll
    for (int rr = 0; rr < 2; ++rr) {
        const int r = wv + 8 * rr;
        const float* xr = x + (size_t)(row0 + r) * 784;
        #pragma unroll
        for (int k = 0; k < 13; ++k) {
            const int idx = k * 64 + lane;
            const bool bit = (idx < 784) && (xr[idx] >= 0.5f);
            unsigned long long m = __ballot(bit);
            if (lane == 0) *(uint64_t*)(&bufA[r][2 * k]) = m;
        }
        if (lane == 0) {
            *(uint64_t*)(&bufA[r][26]) = 0ull;
            *(uint64_t*)(&bufA[r][28]) = 0ull;
            *(uint64_t*)(&bufA[r][30]) = 0ull;
        }
    }
    __syncthreads();

    const uint32_t* Wbase[3] = { ws + OFF_W1/4, ws + OFF_W2/4, ws + OFF_W3/4 };
    const int*      Tbase[3] = { (const int*)(ws + OFF_T1/4), (const int*)(ws + OFF_T2/4), (const int*)(ws + OFF_T3/4) };

    uint32_t (*cur)[32] = bufA;
    uint32_t (*nxt)[32] = bufB;
    const int c0 = t, c1 = t + 512;

    for (int l = 0; l < 3; ++l) {
        uint32_t W0[32], W1[32];
        {
            const uint4* p0 = (const uint4*)(Wbase[l] + (size_t)c0 * 32);
            const uint4* p1 = (const uint4*)(Wbase[l] + (size_t)c1 * 32);
            #pragma unroll
            for (int i = 0; i < 8; ++i) { ((uint4*)W0)[i] = p0[i]; ((uint4*)W1)[i] = p1[i]; }
        }
        const int T0 = Tbase[l][c0];
        const int T1 = Tbase[l][c1];

        for (int r = 0; r < RWS; ++r) {
            uint32_t A[32];
            #pragma unroll
            for (int i = 0; i < 8; ++i) ((uint4*)A)[i] = ((const uint4*)cur[r])[i];
            int pa = 0, pb = 0, pc = 0, pd = 0;
            #pragma unroll
            for (int i = 0; i < 16; ++i) {
                pa += __popc(A[i]      ^ W0[i]);
                pb += __popc(A[i + 16] ^ W0[i + 16]);
                pc += __popc(A[i]      ^ W1[i]);
                pd += __popc(A[i + 16] ^ W1[i + 16]);
            }
            unsigned long long m0 = __ballot((pa + pb) <= T0);
            unsigned long long m1 = __ballot((pc + pd) <= T1);
            if (lane == 0) {
                *(uint64_t*)(&nxt[r][2 * wv])      = m0;
                *(uint64_t*)(&nxt[r][16 + 2 * wv]) = m1;
            }
        }
        __syncthreads();
        uint32_t (*tmp)[32] = cur; cur = nxt; nxt = tmp;
    }

    if (t < RWS * 10) {
        const float sfc = (float)(*(const double*)(ws + OFF_SFC/4));
        const uint32_t* Wfc = ws + OFF_WFC/4;
        const int r = t / 10, ch = t % 10;
        const uint32_t* wrow = Wfc + ch * 32;
        int p = 0;
        #pragma unroll
        for (int i = 0; i < 32; ++i) p += __popc(cur[r][i] ^ wrow[i]);
        out[(size_t)(row0 + r) * 10 + ch] = (float)(1024 - 2 * p) * sfc + bfc[ch];
    }
}

extern "C" void kernel_launch(void* const* d_in, const int* in_sizes, int n_in,
                              void* d_out, int out_size, void* d_ws, size_t ws_size,
                              hipStream_t stream) {
    const float* x   = (const float*)d_in[0];
    const float* w1  = (const float*)d_in[1];
    const float* b1  = (const float*)d_in[2];
    const float* g1  = (const float*)d_in[3];
    const float* be1 = (const float*)d_in[4];
    const float* m1  = (const float*)d_in[5];
    const float* v1  = (const float*)d_in[6];
    const float* w2  = (const float*)d_in[7];
    const float* b2  = (const float*)d_in[8];
    const float* g2  = (const float*)d_in[9];
    const float* be2 = (const float*)d_in[10];
    const float* m2  = (const float*)d_in[11];
    const float* v2  = (const float*)d_in[12];
    const float* w3  = (const float*)d_in[13];
    const float* b3  = (const float*)d_in[14];
    const float* g3  = (const float*)d_in[15];
    const float* be3 = (const float*)d_in[16];
    const float* m3  = (const float*)d_in[17];
    const float* v3  = (const float*)d_in[18];
    const float* wfc = (const float*)d_in[19];
    const float* bfc = (const float*)d_in[20];
    uint32_t* ws = (uint32_t*)d_ws;
    float* out = (float*)d_out;

    // 2 dispatches total: weight prep, then the whole net fused.
    bnn_prep<<<385, 256, 0, stream>>>(
        w1, b1, g1, be1, m1, v1,
        w2, b2, g2, be2, m2, v2,
        w3, b3, g3, be3, m3, v3,
        wfc, ws);

    if (ws_size >= (size_t)WS_NEED_V4) {
        bnn_fused<<<8192 / RWS, 1024, 0, stream>>>(x, ws, bfc, out);
    } else {
        bnn_fused_lds<<<8192 / RWS, 512, 0, stream>>>(x, ws, bfc, out);
    }
}